// Round 2
// baseline (552.333 us; speedup 1.0000x reference)
//
#include <hip/hip_runtime.h>
#include <hip/hip_bf16.h>
#include <math.h>

// NeuralTMT fused scorer.
// Inputs (setup_inputs order):
//  0 IL      [4, V, 64] f32
//  1 LI      [4, V, 64] f32
//  2 UI      [4, U, 64] f32
//  3 IU      [V, 64]    f32
//  4 alpha   [4]        f32
//  5 uid     [B]        i32
//  6 baskets [4, B, L]  i32
//  7 iid     [4, B]     i32
//  8 neg_iid [4, B]     i32
// Output: concat(pos0, neg0, pos1, neg1, pos2, neg2, pos3, neg3), each [B], FLOAT32
// (reference output dtype is f32 — R1 failed because we wrote bf16 into an f32 buffer).

#define NEG_BIG_F (-4294967295.0f)  // -(2^32) + 1

__device__ __forceinline__ float wave_allreduce_sum(float v) {
    // full 64-lane butterfly: every lane ends with the sum
    #pragma unroll
    for (int off = 32; off > 0; off >>= 1) v += __shfl_xor(v, off, 64);
    return v;
}

__global__ __launch_bounds__(256) void neuraltmt_kernel(
    const float* __restrict__ IL, const float* __restrict__ LI,
    const float* __restrict__ UI, const float* __restrict__ IU,
    const float* __restrict__ alpha,
    const int* __restrict__ uid, const int* __restrict__ baskets,
    const int* __restrict__ iid, const int* __restrict__ neg_iid,
    float* __restrict__ out,
    int Bn, int V, int Ln, int U)
{
    const int b    = blockIdx.x;
    const int lane = threadIdx.x & 63;
    const int w    = threadIdx.x >> 6;   // wave id 0..3: s in phase 1, p in phase 2
    const int n_items = V - 1;

    __shared__ float xs[4][64];          // x[b, s, k] for this b

    // ---------- Phase 1: wave w computes x[b, s=w, :] (lane = k) ----------
    {
        const int*   bk  = baskets + ((size_t)w * Bn + b) * (size_t)Ln;
        const float* LIs = LI + (size_t)w * V * 64;
        float acc = 0.0f;
        for (int l = 0; l < Ln; ++l) {
            int idx = bk[l];                       // wave-uniform broadcast load
            if (idx != n_items)                    // padding row (exact reference semantics)
                acc += LIs[(size_t)idx * 64 + lane];  // coalesced 256B row read
        }
        xs[w][lane] = acc / (float)Ln;             // mean over L (reference divides by L)
    }
    __syncthreads();

    // ---------- Phase 2: wave w = period p ----------
    const int p = w;
    const float a  = alpha[p];
    const float sg = 1.0f / (1.0f + expf(-a));     // sigmoid(alpha[p])

    const int ip  = iid[(size_t)p * Bn + b];
    const int in_ = neg_iid[(size_t)p * Bn + b];

    const float* ILp = IL + (size_t)p * V * 64;
    const float tpos = ILp[(size_t)ip  * 64 + lane];
    const float tneg = ILp[(size_t)in_ * 64 + lane];

    // 4 dots per target: d[s] = <x[b,s,:], tgt>
    float dpos[4], dneg[4];
    #pragma unroll
    for (int s = 0; s < 4; ++s) {
        float xv = xs[s][lane];
        dpos[s] = wave_allreduce_sum(xv * tpos);
        dneg[s] = wave_allreduce_sum(xv * tneg);
    }

    // attention: w[s] = d[s]/sqrt(64); exact-zero -> NEG_BIG; softmax over s;
    // score = sum_s softmax(w)[s] * d[s]   (d unscaled in the numerator, per reference)
    auto attend = [&](const float d[4]) -> float {
        float wv[4], m = -INFINITY;
        #pragma unroll
        for (int s = 0; s < 4; ++s) {
            wv[s] = (d[s] == 0.0f) ? NEG_BIG_F : d[s] * 0.125f;
            m = fmaxf(m, wv[s]);
        }
        float den = 0.0f, num = 0.0f;
        #pragma unroll
        for (int s = 0; s < 4; ++s) {
            float e = expf(wv[s] - m);
            den += e;
            num += e * d[s];
        }
        return num / den;
    };
    const float attn_pos = attend(dpos);
    const float attn_neg = attend(dneg);

    // MF term: <UI[p, uid[b]], IU[iid]> and <.., IU[neg_iid]>
    const int u = uid[b];
    const float uv = UI[((size_t)p * U + u) * 64 + lane];
    float mp = wave_allreduce_sum(uv * IU[(size_t)ip  * 64 + lane]);
    float mn = wave_allreduce_sum(uv * IU[(size_t)in_ * 64 + lane]);

    if (lane == 0) {
        float pos = sg * attn_pos + (1.0f - sg) * mp;
        float neg = sg * attn_neg + (1.0f - sg) * mn;
        out[(size_t)(2 * p)     * Bn + b] = pos;   // pos[p] chunk
        out[(size_t)(2 * p + 1) * Bn + b] = neg;   // neg[p] chunk
    }
}

extern "C" void kernel_launch(void* const* d_in, const int* in_sizes, int n_in,
                              void* d_out, int out_size, void* d_ws, size_t ws_size,
                              hipStream_t stream) {
    const float* IL      = (const float*)d_in[0];
    const float* LI      = (const float*)d_in[1];
    const float* UI      = (const float*)d_in[2];
    const float* IU      = (const float*)d_in[3];
    const float* alpha   = (const float*)d_in[4];
    const int*   uid     = (const int*)d_in[5];
    const int*   baskets = (const int*)d_in[6];
    const int*   iid     = (const int*)d_in[7];
    const int*   neg_iid = (const int*)d_in[8];

    const int Bn = in_sizes[5];                 // 16384
    const int V  = in_sizes[3] / 64;            // 100001 (IU is [V,64])
    const int U  = in_sizes[2] / (4 * 64);      // 100000
    const int Ln = in_sizes[6] / (4 * Bn);      // 50

    float* out = (float*)d_out;

    neuraltmt_kernel<<<Bn, 256, 0, stream>>>(IL, LI, UI, IU, alpha,
                                             uid, baskets, iid, neg_iid,
                                             out, Bn, V, Ln, U);
}

// Round 3
// 354.771 us; speedup vs baseline: 1.5569x; 1.5569x over previous
//
#include <hip/hip_runtime.h>
#include <hip/hip_bf16.h>
#include <math.h>

// NeuralTMT fused scorer — R3: latency-bound fix.
// R2 post-mortem: 345 us, HBM 17%, VALU 20%, occupancy 89% => dependent-load
// latency chain in the basket gather (idx load -> row load serialized per
// iteration, ~1820 cyc/iter). Fix: preload all L indices in ONE coalesced
// load (lane l holds bk[l]), broadcast via __shfl, and issue row gathers in
// unrolled batches of 10 so ~10 loads/wave are in flight. Branch replaced by
// select so the compiler can software-pipeline.
//
// Inputs (setup_inputs order):
//  0 IL [4,V,64] f32 | 1 LI [4,V,64] f32 | 2 UI [4,U,64] f32 | 3 IU [V,64] f32
//  4 alpha [4] f32   | 5 uid [B] i32     | 6 baskets [4,B,L] i32
//  7 iid [4,B] i32   | 8 neg_iid [4,B] i32
// Output: concat(pos0,neg0,pos1,neg1,pos2,neg2,pos3,neg3), each [B], f32.

#define NEG_BIG_F (-4294967295.0f)  // -(2^32) + 1

__device__ __forceinline__ float wave_allreduce_sum(float v) {
    #pragma unroll
    for (int off = 32; off > 0; off >>= 1) v += __shfl_xor(v, off, 64);
    return v;
}

__global__ __launch_bounds__(256) void neuraltmt_kernel(
    const float* __restrict__ IL, const float* __restrict__ LI,
    const float* __restrict__ UI, const float* __restrict__ IU,
    const float* __restrict__ alpha,
    const int* __restrict__ uid, const int* __restrict__ baskets,
    const int* __restrict__ iid, const int* __restrict__ neg_iid,
    float* __restrict__ out,
    int Bn, int V, int Ln, int U)
{
    const int b    = blockIdx.x;
    const int lane = threadIdx.x & 63;
    const int w    = threadIdx.x >> 6;   // wave id 0..3: s in phase 1, p in phase 2
    const int n_items = V - 1;

    __shared__ float xs[4][64];          // x[b, s, k] for this b

    // ---------- Phase 1: wave w computes x[b, s=w, :] (lane = k) ----------
    {
        const int*   bk  = baskets + ((size_t)w * Bn + b) * (size_t)Ln;
        const float* LIs = LI + (size_t)w * V * 64;

        // Preload all indices with one coalesced load: lane l holds bk[l].
        int my_idx = (lane < Ln && lane < 64) ? bk[lane] : n_items;

        float acc = 0.0f;
        int l = 0;
        // Batches of 10 independent row gathers in flight.
        for (; l + 10 <= Ln && l + 10 <= 64; l += 10) {
            int   ids[10];
            float v[10];
            #pragma unroll
            for (int j = 0; j < 10; ++j) ids[j] = __shfl(my_idx, l + j, 64);
            #pragma unroll
            for (int j = 0; j < 10; ++j) v[j] = LIs[(size_t)ids[j] * 64 + lane];
            #pragma unroll
            for (int j = 0; j < 10; ++j) acc += (ids[j] != n_items) ? v[j] : 0.0f;
        }
        // Tail within the preloaded window.
        for (; l < Ln && l < 64; ++l) {
            int idx = __shfl(my_idx, l, 64);
            float v = LIs[(size_t)idx * 64 + lane];
            acc += (idx != n_items) ? v : 0.0f;
        }
        // Generic fallback (only if Ln > 64; not hit at L=50).
        for (; l < Ln; ++l) {
            int idx = bk[l];
            float v = LIs[(size_t)idx * 64 + lane];
            acc += (idx != n_items) ? v : 0.0f;
        }
        xs[w][lane] = acc / (float)Ln;   // mean over L (reference divides by L)
    }
    __syncthreads();

    // ---------- Phase 2: wave w = period p ----------
    const int p = w;
    const float a  = alpha[p];
    const float sg = 1.0f / (1.0f + expf(-a));     // sigmoid(alpha[p])

    const int ip  = iid[(size_t)p * Bn + b];
    const int in_ = neg_iid[(size_t)p * Bn + b];
    const int u   = uid[b];

    // Issue all 5 independent row loads up front.
    const float* ILp = IL + (size_t)p * V * 64;
    const float tpos = ILp[(size_t)ip  * 64 + lane];
    const float tneg = ILp[(size_t)in_ * 64 + lane];
    const float uv   = UI[((size_t)p * U + u) * 64 + lane];
    const float iup  = IU[(size_t)ip  * 64 + lane];
    const float iun  = IU[(size_t)in_ * 64 + lane];

    // 4 dots per target: d[s] = <x[b,s,:], tgt>
    float dpos[4], dneg[4];
    #pragma unroll
    for (int s = 0; s < 4; ++s) {
        float xv = xs[s][lane];
        dpos[s] = wave_allreduce_sum(xv * tpos);
        dneg[s] = wave_allreduce_sum(xv * tneg);
    }

    // attention: w[s] = d[s]/sqrt(64); exact-zero -> NEG_BIG; softmax over s;
    // score = sum_s softmax(w)[s] * d[s]  (d unscaled in numerator, per reference)
    auto attend = [&](const float d[4]) -> float {
        float wv[4], m = -INFINITY;
        #pragma unroll
        for (int s = 0; s < 4; ++s) {
            wv[s] = (d[s] == 0.0f) ? NEG_BIG_F : d[s] * 0.125f;
            m = fmaxf(m, wv[s]);
        }
        float den = 0.0f, num = 0.0f;
        #pragma unroll
        for (int s = 0; s < 4; ++s) {
            float e = expf(wv[s] - m);
            den += e;
            num += e * d[s];
        }
        return num / den;
    };
    const float attn_pos = attend(dpos);
    const float attn_neg = attend(dneg);

    float mp = wave_allreduce_sum(uv * iup);
    float mn = wave_allreduce_sum(uv * iun);

    if (lane == 0) {
        float pos = sg * attn_pos + (1.0f - sg) * mp;
        float neg = sg * attn_neg + (1.0f - sg) * mn;
        out[(size_t)(2 * p)     * Bn + b] = pos;   // pos[p] chunk
        out[(size_t)(2 * p + 1) * Bn + b] = neg;   // neg[p] chunk
    }
}

extern "C" void kernel_launch(void* const* d_in, const int* in_sizes, int n_in,
                              void* d_out, int out_size, void* d_ws, size_t ws_size,
                              hipStream_t stream) {
    const float* IL      = (const float*)d_in[0];
    const float* LI      = (const float*)d_in[1];
    const float* UI      = (const float*)d_in[2];
    const float* IU      = (const float*)d_in[3];
    const float* alpha   = (const float*)d_in[4];
    const int*   uid     = (const int*)d_in[5];
    const int*   baskets = (const int*)d_in[6];
    const int*   iid     = (const int*)d_in[7];
    const int*   neg_iid = (const int*)d_in[8];

    const int Bn = in_sizes[5];                 // 16384
    const int V  = in_sizes[3] / 64;            // 100001 (IU is [V,64])
    const int U  = in_sizes[2] / (4 * 64);      // 100000
    const int Ln = in_sizes[6] / (4 * Bn);      // 50

    float* out = (float*)d_out;

    neuraltmt_kernel<<<Bn, 256, 0, stream>>>(IL, LI, UI, IU, alpha,
                                             uid, baskets, iid, neg_iid,
                                             out, Bn, V, Ln, U);
}